// Round 5
// baseline (3997.849 us; speedup 1.0000x reference)
//
#include <hip/hip_runtime.h>
#include <cstddef>
#include <cstdint>
#include <math.h>

#define BB 64
#define PP 196
#define ENCD 512
#define DECD 512
#define ATTD 512
#define VOC 10000
#define CLSE 512
#define MAXLEN 52
#define MAXT 51
#define G4 2048
#define XDIM 1536

// ---- d_out offsets (float elements) ----
#define OFF_PRED 0
#define OFF_CAPS (BB * MAXT * VOC)
#define OFF_DECLEN (OFF_CAPS + BB * MAXLEN)
#define OFF_SORT (OFF_DECLEN + BB)

// ---- workspace offsets (4-byte units) ----
static constexpr size_t W_SORT   = 0;
static constexpr size_t W_DECLEN = 64;
static constexpr size_t W_CAPS   = 128;                      // int[64*52]
static constexpr size_t W_CLS    = 3584;
static constexpr size_t W_H      = W_CLS + BB * CLSE;
static constexpr size_t W_C      = W_H + BB * DECD;
static constexpr size_t W_ININ   = W_C + BB * DECD;
static constexpr size_t W_Z      = W_ININ + BB * 1024;       // f32[64*3072]
static constexpr size_t W_AWE    = W_Z + BB * 3072;          // f32[64*512]
static constexpr size_t W_CLSPRE = W_AWE + BB * ENCD;        // f32[64*2048]
static constexpr size_t W_W1P    = W_CLSPRE + BB * G4;       // f32[256*12*512]
static constexpr size_t W_W2P    = W_W1P + (size_t)256 * 12 * 512;   // f32[256*8*1024]
static constexpr size_t W_HALL   = W_W2P + (size_t)256 * 8 * 1024;   // f32[64*51*512]
static constexpr size_t W_ATT1   = W_HALL + (size_t)BB * MAXT * DECD;
static constexpr size_t W_CNT    = W_ATT1 + (size_t)BB * PP * ATTD;  // int[51*64]
static constexpr size_t W_PAWE   = W_CNT + 3264;             // f32[64*4*520]
static constexpr size_t W_CPRE2  = W_PAWE + (size_t)BB * 4 * 520;    // f32[51*64*2048]
static constexpr size_t W_END    = W_CPRE2 + (size_t)MAXT * BB * G4;

__device__ __forceinline__ float sigm(float x) { return 1.f / (1.f + expf(-x)); }

// MALL-coherent (agent-scope, relaxed) access helpers for intra-kernel fan-in.
__device__ __forceinline__ double cohLd(const double* p) {
    return __hip_atomic_load(p, __ATOMIC_RELAXED, __HIP_MEMORY_SCOPE_AGENT);
}
__device__ __forceinline__ float cohLdF(const float* p) {
    return __hip_atomic_load(p, __ATOMIC_RELAXED, __HIP_MEMORY_SCOPE_AGENT);
}
__device__ __forceinline__ void cohSt(double* p, double v) {
    __hip_atomic_store(p, v, __ATOMIC_RELAXED, __HIP_MEMORY_SCOPE_AGENT);
}
__device__ __forceinline__ void cohStF(float* p, float v) {
    __hip_atomic_store(p, v, __ATOMIC_RELAXED, __HIP_MEMORY_SCOPE_AGENT);
}

// ---------------- setup: stable descending argsort + fan-in counter init ----------------
__global__ void setup_kernel(const int* __restrict__ cap_len, float* __restrict__ out,
                             int* __restrict__ sortind, int* __restrict__ declen,
                             int* __restrict__ cnt) {
    __shared__ int sl[BB];
    int i = threadIdx.x;
    for (int k = i; k < 3264; k += 64) cnt[k] = 0;
    sl[i] = cap_len[i];
    __syncthreads();
    int li = sl[i];
    int rank = 0;
    for (int j = 0; j < BB; j++) {
        int lj = sl[j];
        rank += (lj > li) || (lj == li && j < i);
    }
    sortind[rank] = i;
    declen[rank] = li - 1;
    out[OFF_SORT + rank] = (float)i;
    out[OFF_DECLEN + rank] = (float)(li - 1);
}

// ---------------- gather caps (sorted) + cls_emb (UNSORTED) ----------------
__global__ void gather_kernel(const int* __restrict__ ecaps, const int* __restrict__ classk,
                              const float* __restrict__ clsW, const int* __restrict__ sortind,
                              int* __restrict__ caps_i, float* __restrict__ cls,
                              float* __restrict__ out) {
    int idx = blockIdx.x * 256 + threadIdx.x;
    if (idx < BB * MAXLEN) {
        int b = idx / MAXLEN, t2 = idx - b * MAXLEN;
        int sb = sortind[b];
        int v = ecaps[sb * MAXLEN + t2];
        caps_i[idx] = v;
        out[OFF_CAPS + idx] = (float)v;
    }
    int j = idx - BB * MAXLEN;
    if (j >= 0 && j < BB * CLSE) {
        int row = j >> 9, k = j & 511;
        int ck = classk[row];
        cls[j] = clsW[ck * CLSE + k];
    }
}

// ---------------- mean over P + build init_in ----------------
__global__ void mean_cls_kernel(const float* __restrict__ enc, const float* __restrict__ cls,
                                const int* __restrict__ sortind, float* __restrict__ initin) {
    int b = blockIdx.x;
    int sb = sortind[b];
    for (int k = threadIdx.x; k < ENCD; k += 256) {
        const float* ep = enc + (size_t)sb * PP * ENCD + k;
        float s = 0.f;
        for (int p = 0; p < PP; p++) s += ep[(size_t)p * ENCD];
        initin[b * 1024 + k] = s * (1.f / 196.f);
        initin[b * 1024 + 512 + k] = cls[b * CLSE + k];
    }
}

// ---------------- h0 / c0 ----------------
__global__ void init_hc_kernel(const float* __restrict__ initin,
                               const float* __restrict__ hW, const float* __restrict__ hb,
                               const float* __restrict__ cW, const float* __restrict__ cb,
                               float* __restrict__ h, float* __restrict__ c) {
    int gid = blockIdx.x * 256 + threadIdx.x; // < 65536
    int j = gid & 511, b = (gid >> 9) & 63, which = gid >> 15;
    const float* W = which ? cW : hW;
    const float* bias = which ? cb : hb;
    const float* x = initin + b * 1024;
    float acc = bias[j];
    for (int k = 0; k < 1024; k++) acc += x[k] * W[(size_t)k * 512 + j];
    (which ? c : h)[b * 512 + j] = acc;
}

// ---------------- weight packing: W1p[j][cc][k], cc<12, col=j*12+cc ----------------
__global__ void pack_w1p_kernel(const float* __restrict__ dA, const float* __restrict__ fB,
                                const float* __restrict__ whh, float* __restrict__ W1p) {
    int gid = blockIdx.x * 256 + threadIdx.x; // < 256*12*512
    int k = gid & 511, cc = (gid >> 9) % 12, jb = gid / (512 * 12);
    int q = jb * 12 + cc;
    float v;
    if (q < 512) v = dA[k * 512 + q];
    else if (q < 1024) v = fB[k * 512 + (q - 512)];
    else v = whh[(size_t)(q - 1024) * 512 + k];
    W1p[gid] = v;
}

// W2p[j][cc][k], cc<8: gate=cc>>1, dd=cc&1, gcol=512*gate+2j+dd
__global__ void pack_w2p_kernel(const float* __restrict__ wih, float* __restrict__ W2p) {
    int gid = blockIdx.x * 256 + threadIdx.x; // < 256*8*1024
    int k = gid & 1023, cc = (gid >> 10) & 7, jb = gid >> 13;
    int gcol = 512 * (cc >> 1) + 2 * jb + (cc & 1);
    W2p[gid] = wih[(size_t)gcol * XDIM + k];
}

// ---------------- att1 = enc_sorted @ enc_att_W + b ----------------
__global__ __launch_bounds__(256)
void att1_kernel(const float* __restrict__ enc, const float* __restrict__ Wa,
                 const float* __restrict__ ba, const int* __restrict__ sortind,
                 float* __restrict__ att1) {
    __shared__ float As[16][68];
    __shared__ float Bs[16][64];
    int tid = threadIdx.x;
    int n0 = blockIdx.x * 64, m0 = blockIdx.y * 64;
    int tx = tid & 15, ty = tid >> 4;
    int lm = tid >> 2, lk4 = (tid & 3) * 4;
    int bkk = tid >> 4, bnn4 = (tid & 15) * 4;
    int gm = m0 + lm;
    int b = gm / PP, p = gm - b * PP;
    int sb = sortind[b];
    const float* arow = enc + ((size_t)sb * PP + p) * ENCD;
    float acc[4][4] = {};
    for (int k0 = 0; k0 < ENCD; k0 += 16) {
        float4 av = *(const float4*)(arow + k0 + lk4);
        float4 bv = *(const float4*)(Wa + (size_t)(k0 + bkk) * 512 + n0 + bnn4);
        __syncthreads();
        As[lk4 + 0][lm] = av.x; As[lk4 + 1][lm] = av.y;
        As[lk4 + 2][lm] = av.z; As[lk4 + 3][lm] = av.w;
        *(float4*)&Bs[bkk][bnn4] = bv;
        __syncthreads();
#pragma unroll
        for (int kk = 0; kk < 16; kk++) {
            float4 a4 = *(const float4*)&As[kk][ty * 4];
            float4 b4 = *(const float4*)&Bs[kk][tx * 4];
            acc[0][0] = fmaf(a4.x, b4.x, acc[0][0]); acc[0][1] = fmaf(a4.x, b4.y, acc[0][1]);
            acc[0][2] = fmaf(a4.x, b4.z, acc[0][2]); acc[0][3] = fmaf(a4.x, b4.w, acc[0][3]);
            acc[1][0] = fmaf(a4.y, b4.x, acc[1][0]); acc[1][1] = fmaf(a4.y, b4.y, acc[1][1]);
            acc[1][2] = fmaf(a4.y, b4.z, acc[1][2]); acc[1][3] = fmaf(a4.y, b4.w, acc[1][3]);
            acc[2][0] = fmaf(a4.z, b4.x, acc[2][0]); acc[2][1] = fmaf(a4.z, b4.y, acc[2][1]);
            acc[2][2] = fmaf(a4.z, b4.z, acc[2][2]); acc[2][3] = fmaf(a4.z, b4.w, acc[2][3]);
            acc[3][0] = fmaf(a4.w, b4.x, acc[3][0]); acc[3][1] = fmaf(a4.w, b4.y, acc[3][1]);
            acc[3][2] = fmaf(a4.w, b4.z, acc[3][2]); acc[3][3] = fmaf(a4.w, b4.w, acc[3][3]);
        }
    }
#pragma unroll
    for (int i = 0; i < 4; i++) {
        int m = m0 + ty * 4 + i;
        int n = n0 + tx * 4;
        float4 o;
        o.x = acc[i][0] + ba[n + 0];
        o.y = acc[i][1] + ba[n + 1];
        o.z = acc[i][2] + ba[n + 2];
        o.w = acc[i][3] + ba[n + 3];
        *(float4*)(att1 + (size_t)m * ATTD + n) = o;
    }
}

// ---------------- clspre = cls @ Wih[:,1024:1536]^T + bih + bhh ----------------
__global__ __launch_bounds__(256)
void clspre_kernel(const float* __restrict__ cls, const float* __restrict__ wih,
                   const float* __restrict__ bih, const float* __restrict__ bhh,
                   float* __restrict__ clspre) {
    __shared__ float As[16][68];
    __shared__ float Bs[16][68];
    int tid = threadIdx.x;
    int n0 = blockIdx.x * 64;
    int tx = tid & 15, ty = tid >> 4;
    int lm = tid >> 2, lk4 = (tid & 3) * 4;
    int bnn = tid & 63, bkk4 = (tid >> 6) * 4;
    float acc[4][4] = {};
    for (int k0 = 0; k0 < 512; k0 += 16) {
        float4 av = *(const float4*)(cls + lm * CLSE + k0 + lk4);
        float4 bv = *(const float4*)(wih + (size_t)(n0 + bnn) * XDIM + 1024 + k0 + bkk4);
        __syncthreads();
        As[lk4 + 0][lm] = av.x; As[lk4 + 1][lm] = av.y;
        As[lk4 + 2][lm] = av.z; As[lk4 + 3][lm] = av.w;
        Bs[bkk4 + 0][bnn] = bv.x; Bs[bkk4 + 1][bnn] = bv.y;
        Bs[bkk4 + 2][bnn] = bv.z; Bs[bkk4 + 3][bnn] = bv.w;
        __syncthreads();
#pragma unroll
        for (int kk = 0; kk < 16; kk++) {
            float4 a4 = *(const float4*)&As[kk][ty * 4];
            float4 b4 = *(const float4*)&Bs[kk][tx * 4];
            acc[0][0] = fmaf(a4.x, b4.x, acc[0][0]); acc[0][1] = fmaf(a4.x, b4.y, acc[0][1]);
            acc[0][2] = fmaf(a4.x, b4.z, acc[0][2]); acc[0][3] = fmaf(a4.x, b4.w, acc[0][3]);
            acc[1][0] = fmaf(a4.y, b4.x, acc[1][0]); acc[1][1] = fmaf(a4.y, b4.y, acc[1][1]);
            acc[1][2] = fmaf(a4.y, b4.z, acc[1][2]); acc[1][3] = fmaf(a4.y, b4.w, acc[1][3]);
            acc[2][0] = fmaf(a4.z, b4.x, acc[2][0]); acc[2][1] = fmaf(a4.z, b4.y, acc[2][1]);
            acc[2][2] = fmaf(a4.z, b4.z, acc[2][2]); acc[2][3] = fmaf(a4.z, b4.w, acc[2][3]);
            acc[3][0] = fmaf(a4.w, b4.x, acc[3][0]); acc[3][1] = fmaf(a4.w, b4.y, acc[3][1]);
            acc[3][2] = fmaf(a4.w, b4.z, acc[3][2]); acc[3][3] = fmaf(a4.w, b4.w, acc[3][3]);
        }
    }
#pragma unroll
    for (int i = 0; i < 4; i++) {
        int m = ty * 4 + i;
#pragma unroll
        for (int jj = 0; jj < 4; jj++) {
            int n = n0 + tx * 4 + jj;
            clspre[m * G4 + n] = acc[i][jj] + bih[n] + bhh[n];
        }
    }
}

// ---------------- embpre: cpre2[t][b][gcol] = emb[caps[b,t]] @ Wih[:, :512]^T + clspre[b] ----
__global__ __launch_bounds__(256)
void embpre_kernel(const float* __restrict__ embW, const float* __restrict__ wih,
                   const float* __restrict__ clspreg, const int* __restrict__ caps_i,
                   float* __restrict__ cpre2) {
    __shared__ float As[16][68];
    __shared__ float Bs[16][68];
    int tid = threadIdx.x;
    int n0 = blockIdx.x * 64, t = blockIdx.y;
    int tx = tid & 15, ty = tid >> 4;
    int lm = tid >> 2, lk4 = (tid & 3) * 4;
    int bnn = tid & 63, bkk4 = (tid >> 6) * 4;
    const int cap = caps_i[lm * MAXLEN + t];
    const float* arow = embW + ((size_t)cap << 9);
    float acc[4][4] = {};
    for (int k0 = 0; k0 < 512; k0 += 16) {
        float4 av = *(const float4*)(arow + k0 + lk4);
        float4 bv = *(const float4*)(wih + (size_t)(n0 + bnn) * XDIM + k0 + bkk4);
        __syncthreads();
        As[lk4 + 0][lm] = av.x; As[lk4 + 1][lm] = av.y;
        As[lk4 + 2][lm] = av.z; As[lk4 + 3][lm] = av.w;
        Bs[bkk4 + 0][bnn] = bv.x; Bs[bkk4 + 1][bnn] = bv.y;
        Bs[bkk4 + 2][bnn] = bv.z; Bs[bkk4 + 3][bnn] = bv.w;
        __syncthreads();
#pragma unroll
        for (int kk = 0; kk < 16; kk++) {
            float4 a4 = *(const float4*)&As[kk][ty * 4];
            float4 b4 = *(const float4*)&Bs[kk][tx * 4];
            acc[0][0] = fmaf(a4.x, b4.x, acc[0][0]); acc[0][1] = fmaf(a4.x, b4.y, acc[0][1]);
            acc[0][2] = fmaf(a4.x, b4.z, acc[0][2]); acc[0][3] = fmaf(a4.x, b4.w, acc[0][3]);
            acc[1][0] = fmaf(a4.y, b4.x, acc[1][0]); acc[1][1] = fmaf(a4.y, b4.y, acc[1][1]);
            acc[1][2] = fmaf(a4.y, b4.z, acc[1][2]); acc[1][3] = fmaf(a4.y, b4.w, acc[1][3]);
            acc[2][0] = fmaf(a4.z, b4.x, acc[2][0]); acc[2][1] = fmaf(a4.z, b4.y, acc[2][1]);
            acc[2][2] = fmaf(a4.z, b4.z, acc[2][2]); acc[2][3] = fmaf(a4.z, b4.w, acc[2][3]);
            acc[3][0] = fmaf(a4.w, b4.x, acc[3][0]); acc[3][1] = fmaf(a4.w, b4.y, acc[3][1]);
            acc[3][2] = fmaf(a4.w, b4.z, acc[3][2]); acc[3][3] = fmaf(a4.w, b4.w, acc[3][3]);
        }
    }
#pragma unroll
    for (int i = 0; i < 4; i++) {
        int bl = ty * 4 + i;
        int n = n0 + tx * 4;
        float4 cp = *(const float4*)&clspreg[bl * G4 + n];
        float4 o;
        o.x = acc[i][0] + cp.x; o.y = acc[i][1] + cp.y;
        o.z = acc[i][2] + cp.z; o.w = acc[i][3] + cp.w;
        *(float4*)&cpre2[((size_t)t * 64 + bl) * G4 + n] = o;
    }
}

// ================= per-step kernel 1: Z = h @ W1 + bias (prefetched staging) ==========
__global__ __launch_bounds__(256)
void zstep_kernel(const float* __restrict__ hG, const float* __restrict__ W1p,
                  const float* __restrict__ dab, const float* __restrict__ fbb,
                  float* __restrict__ Zg) {
    const int j = blockIdx.x, tid = threadIdx.x;
    const int lane = tid & 63, wvid = tid >> 6;
    __shared__ float stage[64 * 132];
    __shared__ float W1res[12 * 516];

    for (int idx = tid; idx < 1536; idx += 256) {
        int cc = idx >> 7, pos = (idx & 127) << 2;
        *(float4*)&W1res[cc * 516 + pos] = *(const float4*)&W1p[(size_t)j * 6144 + cc * 512 + pos];
    }
    const int gc0 = j * 12 + wvid, gc1 = gc0 + 4, gc2 = gc0 + 8;
    const float bias0 = (gc0 < 512) ? dab[gc0] : ((gc0 < 1024) ? fbb[gc0 - 512] : 0.f);
    const float bias1 = (gc1 < 512) ? dab[gc1] : ((gc1 < 1024) ? fbb[gc1 - 512] : 0.f);
    const float bias2 = (gc2 < 512) ? dab[gc2] : ((gc2 < 1024) ? fbb[gc2 - 512] : 0.f);

    float4 cur[8];
    {
        const float4* hp = (const float4*)(hG + ((size_t)lane << 9) + (wvid << 5));
#pragma unroll
        for (int i = 0; i < 8; i++) cur[i] = hp[i];
    }
    float a0 = 0.f, a1 = 0.f, a2 = 0.f;
#pragma unroll
    for (int ch = 0; ch < 4; ch++) {
        __syncthreads();
#pragma unroll
        for (int i = 0; i < 8; i++)
            *(float4*)&stage[lane * 132 + (wvid << 5) + (i << 2)] = cur[i];
        __syncthreads();
        if (ch < 3) {
            const float4* hp = (const float4*)(hG + ((size_t)lane << 9) + ((ch + 1) << 7) + (wvid << 5));
#pragma unroll
            for (int i = 0; i < 8; i++) cur[i] = hp[i];
        }
        const float* sp  = &stage[lane * 132];
        const float* w0p = &W1res[wvid * 516 + (ch << 7)];
        const float* w1p = &W1res[(wvid + 4) * 516 + (ch << 7)];
        const float* w2p = &W1res[(wvid + 8) * 516 + (ch << 7)];
#pragma unroll 8
        for (int kk = 0; kk < 128; kk += 4) {
            float4 av = *(const float4*)(sp + kk);
            float4 u0 = *(const float4*)(w0p + kk);
            float4 u1 = *(const float4*)(w1p + kk);
            float4 u2 = *(const float4*)(w2p + kk);
            a0 = fmaf(av.x, u0.x, fmaf(av.y, u0.y, fmaf(av.z, u0.z, fmaf(av.w, u0.w, a0))));
            a1 = fmaf(av.x, u1.x, fmaf(av.y, u1.y, fmaf(av.z, u1.z, fmaf(av.w, u1.w, a1))));
            a2 = fmaf(av.x, u2.x, fmaf(av.y, u2.y, fmaf(av.z, u2.z, fmaf(av.w, u2.w, a2))));
        }
    }
    Zg[lane * 3072 + gc0] = a0 + bias0;
    Zg[lane * 3072 + gc1] = a1 + bias1;
    Zg[lane * 3072 + gc2] = a2 + bias2;
}

// ======== per-step kernel 2: attention, 4-way p-split with lock-free fan-in ========
__global__ __launch_bounds__(256)
void attq_kernel(const float* __restrict__ att1g, const float* __restrict__ encg,
                 const float* __restrict__ Zg, const float* __restrict__ fullw,
                 const float* __restrict__ fullb, const int* __restrict__ sortind,
                 const int* __restrict__ declen, float* __restrict__ paweG,
                 int* __restrict__ cntG, float* __restrict__ aweG, int t) {
    const int blk = blockIdx.x;
    const int b = blk >> 2, q = blk & 3;
    if (t >= declen[b]) return;   // uniform per block
    const int tid = threadIdx.x;
    const int lane = tid & 63, wvid = tid >> 6;

    __shared__ float att2s[512];
    __shared__ float esS[52];
    __shared__ float redA[1], redB[1];
    __shared__ float pawe[4 * 520];
    __shared__ int finS;

    {
        float2 v = *(const float2*)&Zg[b * 3072 + 2 * tid];
        *(float2*)&att2s[2 * tid] = v;
    }
    __syncthreads();

    const float fbv = fullb[0];
    {
        float4 t0 = *(const float4*)&att2s[lane * 8];
        float4 t1 = *(const float4*)&att2s[lane * 8 + 4];
        float4 w0 = *(const float4*)&fullw[lane * 8];
        float4 w1 = *(const float4*)&fullw[lane * 8 + 4];
        const float* a1b = att1g + (size_t)b * PP * 512;
        for (int lp = wvid; lp < 49; lp += 4) {
            int p = 49 * q + lp;
            const float4* ar = (const float4*)(a1b + (size_t)p * 512) + lane * 2;
            float4 u0 = ar[0], u1 = ar[1];
            float s = fmaxf(u0.x + t0.x, 0.f) * w0.x + fmaxf(u0.y + t0.y, 0.f) * w0.y
                    + fmaxf(u0.z + t0.z, 0.f) * w0.z + fmaxf(u0.w + t0.w, 0.f) * w0.w
                    + fmaxf(u1.x + t1.x, 0.f) * w1.x + fmaxf(u1.y + t1.y, 0.f) * w1.y
                    + fmaxf(u1.z + t1.z, 0.f) * w1.z + fmaxf(u1.w + t1.w, 0.f) * w1.w;
#pragma unroll
            for (int off = 32; off; off >>= 1) s += __shfl_down(s, off, 64);
            if (lane == 0) esS[lp] = s + fbv;
        }
    }
    __syncthreads();
    if (tid < 64) {
        float v = (tid < 49) ? esS[tid] : -1e30f;
#pragma unroll
        for (int off = 32; off; off >>= 1) v = fmaxf(v, __shfl_down(v, off, 64));
        if (tid == 0) redA[0] = v;
    }
    __syncthreads();
    const float mq = redA[0];
    if (tid < 64) {
        float ev = (tid < 49) ? expf(esS[tid] - mq) : 0.f;
        float sv = ev;
#pragma unroll
        for (int off = 32; off; off >>= 1) sv += __shfl_down(sv, off, 64);
        if (tid == 0) redB[0] = sv;
        if (tid < 49) esS[tid] = ev;
    }
    __syncthreads();
    const float Sq = redB[0];

    const int sb = sortind[b];
    {
        float aw[8] = {};
        const float* encb = encg + (size_t)sb * PP * 512 + lane;
        for (int lp = wvid; lp < 49; lp += 4) {
            int p = 49 * q + lp;
            float al = esS[lp];
            const float* ep = encb + (size_t)p * 512;
#pragma unroll
            for (int i = 0; i < 8; i++) aw[i] = fmaf(al, ep[i << 6], aw[i]);
        }
#pragma unroll
        for (int i = 0; i < 8; i++) pawe[wvid * 520 + (i << 6) + lane] = aw[i];
    }
    __syncthreads();
    {
        const int k2 = 2 * tid;
        const int base = ((b << 2) + q) * 520;
        float s0 = pawe[k2] + pawe[520 + k2] + pawe[2 * 520 + k2] + pawe[3 * 520 + k2];
        float s1 = pawe[k2 + 1] + pawe[520 + k2 + 1] + pawe[2 * 520 + k2 + 1] + pawe[3 * 520 + k2 + 1];
        double d;
        *(float2*)&d = make_float2(s0, s1);
        cohSt((double*)&paweG[base + k2], d);
        if (tid == 0) {
            cohStF(&paweG[base + 512], Sq);
            cohStF(&paweG[base + 513], mq);
        }
    }
    __syncthreads();   // drains vmcnt: partials are at MALL before arrival

    if (tid == 0) {
        int prev = __hip_atomic_fetch_add(&cntG[t * 64 + b], 1,
                                          __ATOMIC_RELAXED, __HIP_MEMORY_SCOPE_AGENT);
        finS = (prev == 3);
    }
    __syncthreads();
    if (finS) {
        float mv[4], sv[4];
#pragma unroll
        for (int qq = 0; qq < 4; qq++) {
            mv[qq] = cohLdF(&paweG[((b << 2) + qq) * 520 + 513]);
            sv[qq] = cohLdF(&paweG[((b << 2) + qq) * 520 + 512]);
        }
        float M = fmaxf(fmaxf(mv[0], mv[1]), fmaxf(mv[2], mv[3]));
        float f0 = expf(mv[0] - M), f1 = expf(mv[1] - M);
        float f2 = expf(mv[2] - M), f3 = expf(mv[3] - M);
        float inv = 1.f / (sv[0] * f0 + sv[1] * f1 + sv[2] * f2 + sv[3] * f3);
        const int k2 = 2 * tid;
        const double* pd = (const double*)paweG;
        float a0 = 0.f, a1 = 0.f;
        {
            double d0 = cohLd(pd + ((b << 2) + 0) * 260 + tid);
            double d1 = cohLd(pd + ((b << 2) + 1) * 260 + tid);
            double d2 = cohLd(pd + ((b << 2) + 2) * 260 + tid);
            double d3 = cohLd(pd + ((b << 2) + 3) * 260 + tid);
            float2 g0 = *(float2*)&d0, g1 = *(float2*)&d1;
            float2 g2 = *(float2*)&d2, g3 = *(float2*)&d3;
            a0 = g0.x * f0 + g1.x * f1 + g2.x * f2 + g3.x * f3;
            a1 = g0.y * f0 + g1.y * f1 + g2.y * f2 + g3.y * f3;
        }
        float2 gv = *(const float2*)&Zg[b * 3072 + 512 + k2];
        float2 o = make_float2(a0 * inv * sigm(gv.x), a1 * inv * sigm(gv.y));
        *(float2*)&aweG[b * 512 + k2] = o;   // kernel-end release covers next dispatch
    }
}

// ======== per-step kernel 3: gates + LSTM (template: PRE=1 uses precomputed emb) ========
template<int PRE>
__global__ __launch_bounds__(256)
void gatestep_kernel(const float* __restrict__ embW, const float* __restrict__ W2p,
                     const float* __restrict__ cpre, const float* __restrict__ Zg,
                     const float* __restrict__ aweG, const int* __restrict__ caps_i,
                     const int* __restrict__ declen, float* __restrict__ hG,
                     float* __restrict__ cG, float* __restrict__ hall, int t) {
    const int j = blockIdx.x, tid = threadIdx.x;
    const int lane = tid & 63, wvid = tid >> 6;
    const int d0 = j * 2;
    const int NCH = PRE ? 4 : 8;
    const int WST = PRE ? 516 : 1028;
    __shared__ float stage[64 * 132];
    __shared__ float W2res[8 * 1028];
    __shared__ float Gs[8 * 66];
    __shared__ float hhS[64 * 8];
    __shared__ float CsS[64 * 8];
    __shared__ int capS[64];
    __shared__ int declen_s[64];

    if (PRE) {
        for (int idx = tid; idx < 1024; idx += 256) {
            int cc = idx >> 7, pos = (idx & 127) << 2;
            *(float4*)&W2res[cc * 516 + pos] =
                *(const float4*)&W2p[(size_t)j * 8192 + cc * 1024 + 512 + pos];
        }
    } else {
        for (int idx = tid; idx < 2048; idx += 256) {
            int cc = idx >> 8, pos = (idx & 255) << 2;
            *(float4*)&W2res[cc * 1028 + pos] =
                *(const float4*)&W2p[(size_t)j * 8192 + cc * 1024 + pos];
        }
    }
    for (int idx = tid; idx < 512; idx += 256) {
        int r = idx >> 3, cc = idx & 7;
        CsS[idx] = cpre[(r << 11) + ((cc >> 1) << 9) + d0 + (cc & 1)];
    }
    if (tid < 64) {
        if (!PRE) capS[tid] = caps_i[tid * MAXLEN + t];
        declen_s[tid] = declen[tid];
    }
    {
        int r = tid >> 2, g = tid & 3;
        float2 v = *(const float2*)&Zg[r * 3072 + 1024 + (g << 9) + d0];
        hhS[(r << 3) + (g << 1)] = v.x;
        hhS[(r << 3) + (g << 1) + 1] = v.y;
    }
    if (!PRE) __syncthreads();   // capS ready before prefetch uses it

    float4 cur[8];
    {
        const float4* src = PRE
            ? (const float4*)(aweG + ((size_t)lane << 9) + (wvid << 5))
            : (const float4*)(embW + ((size_t)capS[lane] << 9) + (wvid << 5));
#pragma unroll
        for (int i = 0; i < 8; i++) cur[i] = src[i];
    }
    float ac0 = 0.f, ac1 = 0.f;
#pragma unroll
    for (int ch = 0; ch < NCH; ch++) {
        __syncthreads();
#pragma unroll
        for (int i = 0; i < 8; i++)
            *(float4*)&stage[lane * 132 + (wvid << 5) + (i << 2)] = cur[i];
        __syncthreads();
        if (ch + 1 < NCH) {
            int cn = ch + 1;
            const float4* src;
            if (PRE) src = (const float4*)(aweG + ((size_t)lane << 9) + (cn << 7) + (wvid << 5));
            else src = (cn < 4)
                ? (const float4*)(embW + ((size_t)capS[lane] << 9) + (cn << 7) + (wvid << 5))
                : (const float4*)(aweG + ((size_t)lane << 9) + ((cn - 4) << 7) + (wvid << 5));
#pragma unroll
            for (int i = 0; i < 8; i++) cur[i] = src[i];
        }
        const float* sp  = &stage[lane * 132];
        const float* v0p = &W2res[wvid * WST + (ch << 7)];
        const float* v1p = &W2res[(wvid + 4) * WST + (ch << 7)];
#pragma unroll 8
        for (int kk = 0; kk < 128; kk += 4) {
            float4 av = *(const float4*)(sp + kk);
            float4 u0 = *(const float4*)(v0p + kk);
            float4 u1 = *(const float4*)(v1p + kk);
            ac0 = fmaf(av.x, u0.x, fmaf(av.y, u0.y, fmaf(av.z, u0.z, fmaf(av.w, u0.w, ac0))));
            ac1 = fmaf(av.x, u1.x, fmaf(av.y, u1.y, fmaf(av.z, u1.z, fmaf(av.w, u1.w, ac1))));
        }
    }
    Gs[wvid * 66 + lane]       = ac0 + CsS[(lane << 3) + wvid]     + hhS[(lane << 3) + wvid];
    Gs[(wvid + 4) * 66 + lane] = ac1 + CsS[(lane << 3) + wvid + 4] + hhS[(lane << 3) + wvid + 4];
    __syncthreads();
    if (tid < 128) {
        int r2 = tid & 63, dd = tid >> 6;
        if (t < declen_s[r2]) {
            float iv = Gs[(0 + dd) * 66 + r2];
            float fv = Gs[(2 + dd) * 66 + r2];
            float gv = Gs[(4 + dd) * 66 + r2];
            float ov = Gs[(6 + dd) * 66 + r2];
            float cold = cG[r2 * 512 + d0 + dd];
            float cn = sigm(fv) * cold + sigm(iv) * tanhf(gv);
            float hn = sigm(ov) * tanhf(cn);
            cG[r2 * 512 + d0 + dd] = cn;
            hG[r2 * 512 + d0 + dd] = hn;
            hall[((size_t)r2 * MAXT + t) * 512 + d0 + dd] = hn;
        }
    }
}

// ---------------- FC: predictions (masked) : 3264x10000, K=512 ----------------
__global__ __launch_bounds__(256)
void fc_kernel(const float* __restrict__ hall, const float* __restrict__ fcW,
               const float* __restrict__ fcb, const int* __restrict__ declen,
               float* __restrict__ out) {
    __shared__ float As[16][68];
    __shared__ float Bs[16][68];
    int tid = threadIdx.x;
    int n0 = blockIdx.x * 64, m0 = blockIdx.y * 64;
    int tx = tid & 15, ty = tid >> 4;
    int lm = tid >> 2, lk4 = (tid & 3) * 4;
    int bkk = tid >> 4, bnn4 = (tid & 15) * 4;
    const float* arow = hall + (size_t)(m0 + lm) * DECD;
    bool nfull = (n0 + 64 <= VOC);
    float acc[4][4] = {};
    for (int k0 = 0; k0 < 512; k0 += 16) {
        float4 av = *(const float4*)(arow + k0 + lk4);
        float4 bv;
        if (nfull) {
            bv = *(const float4*)(fcW + (size_t)(k0 + bkk) * VOC + n0 + bnn4);
        } else {
            const float* bp = fcW + (size_t)(k0 + bkk) * VOC;
            int nb = n0 + bnn4;
            bv.x = (nb + 0 < VOC) ? bp[nb + 0] : 0.f;
            bv.y = (nb + 1 < VOC) ? bp[nb + 1] : 0.f;
            bv.z = (nb + 2 < VOC) ? bp[nb + 2] : 0.f;
            bv.w = (nb + 3 < VOC) ? bp[nb + 3] : 0.f;
        }
        __syncthreads();
        As[lk4 + 0][lm] = av.x; As[lk4 + 1][lm] = av.y;
        As[lk4 + 2][lm] = av.z; As[lk4 + 3][lm] = av.w;
        *(float4*)&Bs[bkk][bnn4] = bv;
        __syncthreads();
#pragma unroll
        for (int kk = 0; kk < 16; kk++) {
            float4 a4 = *(const float4*)&As[kk][ty * 4];
            float4 b4 = *(const float4*)&Bs[kk][tx * 4];
            acc[0][0] = fmaf(a4.x, b4.x, acc[0][0]); acc[0][1] = fmaf(a4.x, b4.y, acc[0][1]);
            acc[0][2] = fmaf(a4.x, b4.z, acc[0][2]); acc[0][3] = fmaf(a4.x, b4.w, acc[0][3]);
            acc[1][0] = fmaf(a4.y, b4.x, acc[1][0]); acc[1][1] = fmaf(a4.y, b4.y, acc[1][1]);
            acc[1][2] = fmaf(a4.y, b4.z, acc[1][2]); acc[1][3] = fmaf(a4.y, b4.w, acc[1][3]);
            acc[2][0] = fmaf(a4.z, b4.x, acc[2][0]); acc[2][1] = fmaf(a4.z, b4.y, acc[2][1]);
            acc[2][2] = fmaf(a4.z, b4.z, acc[2][2]); acc[2][3] = fmaf(a4.z, b4.w, acc[2][3]);
            acc[3][0] = fmaf(a4.w, b4.x, acc[3][0]); acc[3][1] = fmaf(a4.w, b4.y, acc[3][1]);
            acc[3][2] = fmaf(a4.w, b4.z, acc[3][2]); acc[3][3] = fmaf(a4.w, b4.w, acc[3][3]);
        }
    }
#pragma unroll
    for (int i = 0; i < 4; i++) {
        int m = m0 + ty * 4 + i;
        int b = m / MAXT, t = m - b * MAXT;
        bool act = t < declen[b];
        int n = n0 + tx * 4;
        if (nfull) {
            float4 o;
            o.x = act ? acc[i][0] + fcb[n + 0] : 0.f;
            o.y = act ? acc[i][1] + fcb[n + 1] : 0.f;
            o.z = act ? acc[i][2] + fcb[n + 2] : 0.f;
            o.w = act ? acc[i][3] + fcb[n + 3] : 0.f;
            *(float4*)(out + (size_t)m * VOC + n) = o;
        } else {
#pragma unroll
            for (int jj = 0; jj < 4; jj++) {
                int nn = n + jj;
                if (nn < VOC) out[(size_t)m * VOC + nn] = act ? acc[i][jj] + fcb[nn] : 0.f;
            }
        }
    }
}

extern "C" void kernel_launch(void* const* d_in, const int* in_sizes, int n_in,
                              void* d_out, int out_size, void* d_ws, size_t ws_size,
                              hipStream_t stream) {
    const float* enc     = (const float*)d_in[0];
    const int*   ecaps   = (const int*)d_in[1];
    const int*   lens    = (const int*)d_in[2];
    const int*   classk  = (const int*)d_in[3];
    const float* embW    = (const float*)d_in[4];
    const float* clsW    = (const float*)d_in[5];
    const float* encattW = (const float*)d_in[6];
    const float* encattb = (const float*)d_in[7];
    const float* decattW = (const float*)d_in[8];
    const float* decattb = (const float*)d_in[9];
    const float* fullw   = (const float*)d_in[10];
    const float* fullb   = (const float*)d_in[11];
    const float* ihW     = (const float*)d_in[12];
    const float* ihb     = (const float*)d_in[13];
    const float* icW     = (const float*)d_in[14];
    const float* icb     = (const float*)d_in[15];
    const float* fbW     = (const float*)d_in[16];
    const float* fbb     = (const float*)d_in[17];
    const float* Wih     = (const float*)d_in[18];
    const float* Whh     = (const float*)d_in[19];
    const float* bih     = (const float*)d_in[20];
    const float* bhh     = (const float*)d_in[21];
    const float* fcW     = (const float*)d_in[22];
    const float* fcb     = (const float*)d_in[23];

    float* out = (float*)d_out;
    float* ws  = (float*)d_ws;
    int*   wsi = (int*)d_ws;

    int*   sortind = wsi + W_SORT;
    int*   declen  = wsi + W_DECLEN;
    int*   caps_i  = wsi + W_CAPS;
    float* cls     = ws + W_CLS;
    float* h       = ws + W_H;
    float* c       = ws + W_C;
    float* initin  = ws + W_ININ;
    float* Z       = ws + W_Z;
    float* awe     = ws + W_AWE;
    float* clspre  = ws + W_CLSPRE;
    float* W1p     = ws + W_W1P;
    float* W2p     = ws + W_W2P;
    float* hall    = ws + W_HALL;
    float* att1    = ws + W_ATT1;
    int*   cnt     = wsi + W_CNT;
    float* pawe    = ws + W_PAWE;
    float* cpre2   = ws + W_CPRE2;

    const bool pre = ws_size >= W_END * 4;   // cpre2 fits in workspace?

    setup_kernel<<<1, 64, 0, stream>>>(lens, out, sortind, declen, cnt);
    gather_kernel<<<141, 256, 0, stream>>>(ecaps, classk, clsW, sortind, caps_i, cls, out);
    mean_cls_kernel<<<BB, 256, 0, stream>>>(enc, cls, sortind, initin);
    init_hc_kernel<<<256, 256, 0, stream>>>(initin, ihW, ihb, icW, icb, h, c);
    pack_w1p_kernel<<<6144, 256, 0, stream>>>(decattW, fbW, Whh, W1p);
    pack_w2p_kernel<<<8192, 256, 0, stream>>>(Wih, W2p);
    att1_kernel<<<dim3(8, 196), 256, 0, stream>>>(enc, encattW, encattb, sortind, att1);
    clspre_kernel<<<32, 256, 0, stream>>>(cls, Wih, bih, bhh, clspre);
    if (pre)
        embpre_kernel<<<dim3(32, 51), 256, 0, stream>>>(embW, Wih, clspre, caps_i, cpre2);

    for (int t = 0; t < MAXT; t++) {
        zstep_kernel<<<256, 256, 0, stream>>>(h, W1p, decattb, fbb, Z);
        attq_kernel<<<256, 256, 0, stream>>>(att1, enc, Z, fullw, fullb,
                                             sortind, declen, pawe, cnt, awe, t);
        if (pre)
            gatestep_kernel<1><<<256, 256, 0, stream>>>(embW, W2p,
                cpre2 + (size_t)t * 64 * G4, Z, awe, caps_i, declen, h, c, hall, t);
        else
            gatestep_kernel<0><<<256, 256, 0, stream>>>(embW, W2p,
                clspre, Z, awe, caps_i, declen, h, c, hall, t);
    }

    fc_kernel<<<dim3(157, 51), 256, 0, stream>>>(hall, fcW, fcb, declen, out);
}

// Round 6
// 3719.924 us; speedup vs baseline: 1.0747x; 1.0747x over previous
//
#include <hip/hip_runtime.h>
#include <cstddef>
#include <cstdint>
#include <math.h>

#define BB 64
#define PP 196
#define ENCD 512
#define DECD 512
#define ATTD 512
#define VOC 10000
#define CLSE 512
#define MAXLEN 52
#define MAXT 51
#define G4 2048
#define XDIM 1536

// ---- d_out offsets (float elements) ----
#define OFF_PRED 0
#define OFF_CAPS (BB * MAXT * VOC)
#define OFF_DECLEN (OFF_CAPS + BB * MAXLEN)
#define OFF_SORT (OFF_DECLEN + BB)

// ---- workspace offsets (4-byte units) ----
static constexpr size_t W_SORT   = 0;
static constexpr size_t W_DECLEN = 64;
static constexpr size_t W_CAPS   = 128;                      // int[64*52] ends 3456
static constexpr size_t W_CLS    = 3584;
static constexpr size_t W_H      = W_CLS + BB * CLSE;        // 36352
static constexpr size_t W_C      = W_H + BB * DECD;          // 69120
static constexpr size_t W_ININ   = W_C + BB * DECD;          // 101888
static constexpr size_t W_EXCH   = W_ININ + BB * 1024;       // 167424: f32[64*1024] att2|fg
static constexpr size_t W_AWE    = W_EXCH + BB * 1024;       // 232960
static constexpr size_t W_CLSPRE = W_AWE + BB * ENCD;        // 265728
static constexpr size_t W_W3P    = W_CLSPRE + BB * G4;       // 396800: f32[256*8*512]
static constexpr size_t W_W2P    = W_W3P + (size_t)256 * 8 * 512;    // f32[256*8*1024]
static constexpr size_t W_HALL   = W_W2P + (size_t)256 * 8 * 1024;   // f32[64*51*512]
static constexpr size_t W_ATT1   = W_HALL + (size_t)BB * MAXT * DECD;
static constexpr size_t W_CNTP   = W_ATT1 + (size_t)BB * PP * ATTD;  // int[51*64]
static constexpr size_t W_CNTX   = W_CNTP + 3264;            // int[51*64]
static constexpr size_t W_PAWE   = W_CNTX + 3264;            // f32[64*4*520]
static constexpr size_t W_CPRE2  = W_PAWE + (size_t)BB * 4 * 520;    // f32[51*64*2048]
static constexpr size_t W_END    = W_CPRE2 + (size_t)MAXT * BB * G4;

__device__ __forceinline__ float sigm(float x) { return 1.f / (1.f + expf(-x)); }

// MALL-coherent (agent-scope, relaxed) access helpers for intra-kernel fan-in.
__device__ __forceinline__ double cohLd(const double* p) {
    return __hip_atomic_load(p, __ATOMIC_RELAXED, __HIP_MEMORY_SCOPE_AGENT);
}
__device__ __forceinline__ float cohLdF(const float* p) {
    return __hip_atomic_load(p, __ATOMIC_RELAXED, __HIP_MEMORY_SCOPE_AGENT);
}
__device__ __forceinline__ void cohSt(double* p, double v) {
    __hip_atomic_store(p, v, __ATOMIC_RELAXED, __HIP_MEMORY_SCOPE_AGENT);
}
__device__ __forceinline__ void cohStF(float* p, float v) {
    __hip_atomic_store(p, v, __ATOMIC_RELAXED, __HIP_MEMORY_SCOPE_AGENT);
}

// ---------------- setup: stable descending argsort + counter init ----------------
__global__ void setup_kernel(const int* __restrict__ cap_len, float* __restrict__ out,
                             int* __restrict__ sortind, int* __restrict__ declen,
                             int* __restrict__ cnt) {
    __shared__ int sl[BB];
    int i = threadIdx.x;
    for (int k = i; k < 6528; k += 64) cnt[k] = 0;   // cntP + cntX
    sl[i] = cap_len[i];
    __syncthreads();
    int li = sl[i];
    int rank = 0;
    for (int j = 0; j < BB; j++) {
        int lj = sl[j];
        rank += (lj > li) || (lj == li && j < i);
    }
    sortind[rank] = i;
    declen[rank] = li - 1;
    out[OFF_SORT + rank] = (float)i;
    out[OFF_DECLEN + rank] = (float)(li - 1);
}

// ---------------- gather caps (sorted) + cls_emb (UNSORTED) ----------------
__global__ void gather_kernel(const int* __restrict__ ecaps, const int* __restrict__ classk,
                              const float* __restrict__ clsW, const int* __restrict__ sortind,
                              int* __restrict__ caps_i, float* __restrict__ cls,
                              float* __restrict__ out) {
    int idx = blockIdx.x * 256 + threadIdx.x;
    if (idx < BB * MAXLEN) {
        int b = idx / MAXLEN, t2 = idx - b * MAXLEN;
        int sb = sortind[b];
        int v = ecaps[sb * MAXLEN + t2];
        caps_i[idx] = v;
        out[OFF_CAPS + idx] = (float)v;
    }
    int j = idx - BB * MAXLEN;
    if (j >= 0 && j < BB * CLSE) {
        int row = j >> 9, k = j & 511;
        int ck = classk[row];
        cls[j] = clsW[ck * CLSE + k];
    }
}

// ---------------- mean over P + build init_in ----------------
__global__ void mean_cls_kernel(const float* __restrict__ enc, const float* __restrict__ cls,
                                const int* __restrict__ sortind, float* __restrict__ initin) {
    int b = blockIdx.x;
    int sb = sortind[b];
    for (int k = threadIdx.x; k < ENCD; k += 256) {
        const float* ep = enc + (size_t)sb * PP * ENCD + k;
        float s = 0.f;
        for (int p = 0; p < PP; p++) s += ep[(size_t)p * ENCD];
        initin[b * 1024 + k] = s * (1.f / 196.f);
        initin[b * 1024 + 512 + k] = cls[b * CLSE + k];
    }
}

// ---------------- h0 / c0 ----------------
__global__ void init_hc_kernel(const float* __restrict__ initin,
                               const float* __restrict__ hW, const float* __restrict__ hb,
                               const float* __restrict__ cW, const float* __restrict__ cb,
                               float* __restrict__ h, float* __restrict__ c) {
    int gid = blockIdx.x * 256 + threadIdx.x; // < 65536
    int j = gid & 511, b = (gid >> 9) & 63, which = gid >> 15;
    const float* W = which ? cW : hW;
    const float* bias = which ? cb : hb;
    const float* x = initin + b * 1024;
    float acc = bias[j];
    for (int k = 0; k < 1024; k++) acc += x[k] * W[(size_t)k * 512 + j];
    (which ? c : h)[b * 512 + j] = acc;
}

// W2p[j][cc][k], cc<8, k<1024: gate=cc>>1, dd=cc&1, gcol=512*gate+2j+dd
__global__ void pack_w2p_kernel(const float* __restrict__ wih, float* __restrict__ W2p) {
    int gid = blockIdx.x * 256 + threadIdx.x; // < 256*8*1024
    int k = gid & 1023, cc = (gid >> 10) & 7, jb = gid >> 13;
    int gcol = 512 * (cc >> 1) + 2 * jb + (cc & 1);
    W2p[gid] = wih[(size_t)gcol * XDIM + k];
}

// W3p[j][cc][k], cc<8, k<512: Whh rows for block j's 8 gate cols
__global__ void pack_w3p_kernel(const float* __restrict__ whh, float* __restrict__ W3p) {
    int gid = blockIdx.x * 256 + threadIdx.x; // < 256*8*512
    int k = gid & 511, cc = (gid >> 9) & 7, jb = gid >> 12;
    int gcol = 512 * (cc >> 1) + 2 * jb + (cc & 1);
    W3p[gid] = whh[(size_t)gcol * 512 + k];
}

// ---------------- att1 = enc_sorted @ enc_att_W + b ----------------
__global__ __launch_bounds__(256)
void att1_kernel(const float* __restrict__ enc, const float* __restrict__ Wa,
                 const float* __restrict__ ba, const int* __restrict__ sortind,
                 float* __restrict__ att1) {
    __shared__ float As[16][68];
    __shared__ float Bs[16][64];
    int tid = threadIdx.x;
    int n0 = blockIdx.x * 64, m0 = blockIdx.y * 64;
    int tx = tid & 15, ty = tid >> 4;
    int lm = tid >> 2, lk4 = (tid & 3) * 4;
    int bkk = tid >> 4, bnn4 = (tid & 15) * 4;
    int gm = m0 + lm;
    int b = gm / PP, p = gm - b * PP;
    int sb = sortind[b];
    const float* arow = enc + ((size_t)sb * PP + p) * ENCD;
    float acc[4][4] = {};
    for (int k0 = 0; k0 < ENCD; k0 += 16) {
        float4 av = *(const float4*)(arow + k0 + lk4);
        float4 bv = *(const float4*)(Wa + (size_t)(k0 + bkk) * 512 + n0 + bnn4);
        __syncthreads();
        As[lk4 + 0][lm] = av.x; As[lk4 + 1][lm] = av.y;
        As[lk4 + 2][lm] = av.z; As[lk4 + 3][lm] = av.w;
        *(float4*)&Bs[bkk][bnn4] = bv;
        __syncthreads();
#pragma unroll
        for (int kk = 0; kk < 16; kk++) {
            float4 a4 = *(const float4*)&As[kk][ty * 4];
            float4 b4 = *(const float4*)&Bs[kk][tx * 4];
            float a[4] = {a4.x, a4.y, a4.z, a4.w};
#pragma unroll
            for (int i = 0; i < 4; i++) {
                acc[i][0] = fmaf(a[i], b4.x, acc[i][0]);
                acc[i][1] = fmaf(a[i], b4.y, acc[i][1]);
                acc[i][2] = fmaf(a[i], b4.z, acc[i][2]);
                acc[i][3] = fmaf(a[i], b4.w, acc[i][3]);
            }
        }
    }
#pragma unroll
    for (int i = 0; i < 4; i++) {
        int m = m0 + ty * 4 + i;
        int n = n0 + tx * 4;
        float4 o;
        o.x = acc[i][0] + ba[n + 0];
        o.y = acc[i][1] + ba[n + 1];
        o.z = acc[i][2] + ba[n + 2];
        o.w = acc[i][3] + ba[n + 3];
        *(float4*)(att1 + (size_t)m * ATTD + n) = o;
    }
}

// ---------------- clspre = cls @ Wih[:,1024:1536]^T + bih + bhh ----------------
__global__ __launch_bounds__(256)
void clspre_kernel(const float* __restrict__ cls, const float* __restrict__ wih,
                   const float* __restrict__ bih, const float* __restrict__ bhh,
                   float* __restrict__ clspre) {
    __shared__ float As[16][68];
    __shared__ float Bs[16][68];
    int tid = threadIdx.x;
    int n0 = blockIdx.x * 64;
    int tx = tid & 15, ty = tid >> 4;
    int lm = tid >> 2, lk4 = (tid & 3) * 4;
    int bnn = tid & 63, bkk4 = (tid >> 6) * 4;
    float acc[4][4] = {};
    for (int k0 = 0; k0 < 512; k0 += 16) {
        float4 av = *(const float4*)(cls + lm * CLSE + k0 + lk4);
        float4 bv = *(const float4*)(wih + (size_t)(n0 + bnn) * XDIM + 1024 + k0 + bkk4);
        __syncthreads();
        As[lk4 + 0][lm] = av.x; As[lk4 + 1][lm] = av.y;
        As[lk4 + 2][lm] = av.z; As[lk4 + 3][lm] = av.w;
        Bs[bkk4 + 0][bnn] = bv.x; Bs[bkk4 + 1][bnn] = bv.y;
        Bs[bkk4 + 2][bnn] = bv.z; Bs[bkk4 + 3][bnn] = bv.w;
        __syncthreads();
#pragma unroll
        for (int kk = 0; kk < 16; kk++) {
            float4 a4 = *(const float4*)&As[kk][ty * 4];
            float4 b4 = *(const float4*)&Bs[kk][tx * 4];
            float a[4] = {a4.x, a4.y, a4.z, a4.w};
#pragma unroll
            for (int i = 0; i < 4; i++) {
                acc[i][0] = fmaf(a[i], b4.x, acc[i][0]);
                acc[i][1] = fmaf(a[i], b4.y, acc[i][1]);
                acc[i][2] = fmaf(a[i], b4.z, acc[i][2]);
                acc[i][3] = fmaf(a[i], b4.w, acc[i][3]);
            }
        }
    }
#pragma unroll
    for (int i = 0; i < 4; i++) {
        int m = ty * 4 + i;
#pragma unroll
        for (int jj = 0; jj < 4; jj++) {
            int n = n0 + tx * 4 + jj;
            clspre[m * G4 + n] = acc[i][jj] + bih[n] + bhh[n];
        }
    }
}

// ---------------- embpre: cpre2[t][b][gcol] = emb[caps[b,t]] @ Wih[:, :512]^T + clspre[b] ----
__global__ __launch_bounds__(256)
void embpre_kernel(const float* __restrict__ embW, const float* __restrict__ wih,
                   const float* __restrict__ clspreg, const int* __restrict__ caps_i,
                   float* __restrict__ cpre2) {
    __shared__ float As[16][68];
    __shared__ float Bs[16][68];
    int tid = threadIdx.x;
    int n0 = blockIdx.x * 64, t = blockIdx.y;
    int tx = tid & 15, ty = tid >> 4;
    int lm = tid >> 2, lk4 = (tid & 3) * 4;
    int bnn = tid & 63, bkk4 = (tid >> 6) * 4;
    const int cap = caps_i[lm * MAXLEN + t];
    const float* arow = embW + ((size_t)cap << 9);
    float acc[4][4] = {};
    for (int k0 = 0; k0 < 512; k0 += 16) {
        float4 av = *(const float4*)(arow + k0 + lk4);
        float4 bv = *(const float4*)(wih + (size_t)(n0 + bnn) * XDIM + k0 + bkk4);
        __syncthreads();
        As[lk4 + 0][lm] = av.x; As[lk4 + 1][lm] = av.y;
        As[lk4 + 2][lm] = av.z; As[lk4 + 3][lm] = av.w;
        Bs[bkk4 + 0][bnn] = bv.x; Bs[bkk4 + 1][bnn] = bv.y;
        Bs[bkk4 + 2][bnn] = bv.z; Bs[bkk4 + 3][bnn] = bv.w;
        __syncthreads();
#pragma unroll
        for (int kk = 0; kk < 16; kk++) {
            float4 a4 = *(const float4*)&As[kk][ty * 4];
            float4 b4 = *(const float4*)&Bs[kk][tx * 4];
            float a[4] = {a4.x, a4.y, a4.z, a4.w};
#pragma unroll
            for (int i = 0; i < 4; i++) {
                acc[i][0] = fmaf(a[i], b4.x, acc[i][0]);
                acc[i][1] = fmaf(a[i], b4.y, acc[i][1]);
                acc[i][2] = fmaf(a[i], b4.z, acc[i][2]);
                acc[i][3] = fmaf(a[i], b4.w, acc[i][3]);
            }
        }
    }
#pragma unroll
    for (int i = 0; i < 4; i++) {
        int bl = ty * 4 + i;
        int n = n0 + tx * 4;
        float4 cp = *(const float4*)&clspreg[bl * G4 + n];
        float4 o;
        o.x = acc[i][0] + cp.x; o.y = acc[i][1] + cp.y;
        o.z = acc[i][2] + cp.z; o.w = acc[i][3] + cp.w;
        *(float4*)&cpre2[((size_t)t * 64 + bl) * G4 + n] = o;
    }
}

// ======== per-step kernel A: att2/fg slice + exchange + attention + awe fan-in ========
// 256 blocks: b = blk&63, q = blk>>6. Block computes att2/fg cols [128q,128q+128),
// publishes via relaxed stores + 4-arrival counter (tiny spin), then does its
// p-quarter of e/softmax/awe exactly as the proven r4 fan-in.
__global__ __launch_bounds__(256)
void attq_kernel(const float* __restrict__ att1g, const float* __restrict__ encg,
                 const float* __restrict__ hG, const float* __restrict__ Wd,
                 const float* __restrict__ Fb, const float* __restrict__ dab,
                 const float* __restrict__ fbb, const float* __restrict__ fullw,
                 const float* __restrict__ fullb, const int* __restrict__ sortind,
                 const int* __restrict__ declen, float* __restrict__ exch,
                 float* __restrict__ paweG, int* __restrict__ cntX,
                 int* __restrict__ cntP, float* __restrict__ aweG, int t) {
    const int blk = blockIdx.x;
    const int b = blk & 63, q = blk >> 6;
    if (t >= declen[b]) return;   // uniform across the 4 sibling blocks of b
    const int tid = threadIdx.x;
    const int lane = tid & 63, wvid = tid >> 6;

    __shared__ float hS[512];
    __shared__ float pa[256], pb[256];
    __shared__ float att2F[512];
    __shared__ float esS[52];
    __shared__ float redA[1], redB[1];
    __shared__ float pawe[4 * 520];
    __shared__ int finS;

    hS[tid] = hG[b * 512 + tid];
    hS[tid + 256] = hG[b * 512 + 256 + tid];
    __syncthreads();

    // att2/fg slice: col = 128q + (tid&127), k-half = tid>>7
    {
        const int c = tid & 127, kh = tid >> 7;
        const int col = 128 * q + c;
        const float* wd = Wd + (size_t)(kh << 8) * 512 + col;
        const float* fb = Fb + (size_t)(kh << 8) * 512 + col;
        const float* hp = hS + (kh << 8);
        float a2 = 0.f, fg = 0.f;
#pragma unroll 16
        for (int k = 0; k < 256; k++) {
            float hv = hp[k];
            a2 = fmaf(hv, wd[(size_t)k * 512], a2);
            fg = fmaf(hv, fb[(size_t)k * 512], fg);
        }
        pa[tid] = a2; pb[tid] = fg;
    }
    __syncthreads();
    if (tid < 128) {
        int col = 128 * q + tid;
        cohStF(&exch[b * 1024 + col], pa[tid] + pa[tid + 128] + dab[col]);
        cohStF(&exch[b * 1024 + 512 + col], pb[tid] + pb[tid + 128] + fbb[col]);
    }
    __syncthreads();   // drain vmcnt: slice visible at MALL before arrival
    if (tid == 0) {
        int* cx = &cntX[t * 64 + b];
        __hip_atomic_fetch_add(cx, 1, __ATOMIC_RELAXED, __HIP_MEMORY_SCOPE_AGENT);
        while (__hip_atomic_load(cx, __ATOMIC_RELAXED, __HIP_MEMORY_SCOPE_AGENT) < 4)
            __builtin_amdgcn_s_sleep(2);
    }
    __syncthreads();
    att2F[tid] = cohLdF(&exch[b * 1024 + tid]);
    att2F[tid + 256] = cohLdF(&exch[b * 1024 + 256 + tid]);
    __syncthreads();

    const float fbv = fullb[0];
    // e_p for this quarter's 49 rows (wave per p, lane covers 8 att-dims)
    {
        float4 t0 = *(const float4*)&att2F[lane * 8];
        float4 t1 = *(const float4*)&att2F[lane * 8 + 4];
        float4 w0 = *(const float4*)&fullw[lane * 8];
        float4 w1 = *(const float4*)&fullw[lane * 8 + 4];
        const float* a1b = att1g + (size_t)b * PP * 512;
        for (int lp = wvid; lp < 49; lp += 4) {
            int p = 49 * q + lp;
            const float4* ar = (const float4*)(a1b + (size_t)p * 512) + lane * 2;
            float4 u0 = ar[0], u1 = ar[1];
            float s = fmaxf(u0.x + t0.x, 0.f) * w0.x + fmaxf(u0.y + t0.y, 0.f) * w0.y
                    + fmaxf(u0.z + t0.z, 0.f) * w0.z + fmaxf(u0.w + t0.w, 0.f) * w0.w
                    + fmaxf(u1.x + t1.x, 0.f) * w1.x + fmaxf(u1.y + t1.y, 0.f) * w1.y
                    + fmaxf(u1.z + t1.z, 0.f) * w1.z + fmaxf(u1.w + t1.w, 0.f) * w1.w;
#pragma unroll
            for (int off = 32; off; off >>= 1) s += __shfl_down(s, off, 64);
            if (lane == 0) esS[lp] = s + fbv;
        }
    }
    __syncthreads();
    if (tid < 64) {
        float v = (tid < 49) ? esS[tid] : -1e30f;
#pragma unroll
        for (int off = 32; off; off >>= 1) v = fmaxf(v, __shfl_down(v, off, 64));
        if (tid == 0) redA[0] = v;
    }
    __syncthreads();
    const float mq = redA[0];
    if (tid < 64) {
        float ev = (tid < 49) ? expf(esS[tid] - mq) : 0.f;
        float sv = ev;
#pragma unroll
        for (int off = 32; off; off >>= 1) sv += __shfl_down(sv, off, 64);
        if (tid == 0) redB[0] = sv;
        if (tid < 49) esS[tid] = ev;
    }
    __syncthreads();
    const float Sq = redB[0];

    const int sb = sortind[b];
    {
        float aw[8] = {};
        const float* encb = encg + (size_t)sb * PP * 512 + lane;
        for (int lp = wvid; lp < 49; lp += 4) {
            int p = 49 * q + lp;
            float al = esS[lp];
            const float* ep = encb + (size_t)p * 512;
#pragma unroll
            for (int i = 0; i < 8; i++) aw[i] = fmaf(al, ep[i << 6], aw[i]);
        }
#pragma unroll
        for (int i = 0; i < 8; i++) pawe[wvid * 520 + (i << 6) + lane] = aw[i];
    }
    __syncthreads();
    {
        const int k2 = 2 * tid;
        const int base = ((b << 2) + q) * 520;
        float s0 = pawe[k2] + pawe[520 + k2] + pawe[2 * 520 + k2] + pawe[3 * 520 + k2];
        float s1 = pawe[k2 + 1] + pawe[520 + k2 + 1] + pawe[2 * 520 + k2 + 1] + pawe[3 * 520 + k2 + 1];
        double d;
        *(float2*)&d = make_float2(s0, s1);
        cohSt((double*)&paweG[base + k2], d);
        if (tid == 0) {
            cohStF(&paweG[base + 512], Sq);
            cohStF(&paweG[base + 513], mq);
        }
    }
    __syncthreads();   // drain: partials at MALL before arrival

    if (tid == 0) {
        int prev = __hip_atomic_fetch_add(&cntP[t * 64 + b], 1,
                                          __ATOMIC_RELAXED, __HIP_MEMORY_SCOPE_AGENT);
        finS = (prev == 3);
    }
    __syncthreads();
    if (finS) {
        float mv[4], sv[4];
#pragma unroll
        for (int qq = 0; qq < 4; qq++) {
            mv[qq] = cohLdF(&paweG[((b << 2) + qq) * 520 + 513]);
            sv[qq] = cohLdF(&paweG[((b << 2) + qq) * 520 + 512]);
        }
        float M = fmaxf(fmaxf(mv[0], mv[1]), fmaxf(mv[2], mv[3]));
        float f0 = expf(mv[0] - M), f1 = expf(mv[1] - M);
        float f2 = expf(mv[2] - M), f3 = expf(mv[3] - M);
        float inv = 1.f / (sv[0] * f0 + sv[1] * f1 + sv[2] * f2 + sv[3] * f3);
        const int k2 = 2 * tid;
        const double* pd = (const double*)paweG;
        float a0, a1;
        {
            double d0 = cohLd(pd + ((b << 2) + 0) * 260 + tid);
            double d1 = cohLd(pd + ((b << 2) + 1) * 260 + tid);
            double d2 = cohLd(pd + ((b << 2) + 2) * 260 + tid);
            double d3 = cohLd(pd + ((b << 2) + 3) * 260 + tid);
            float2 g0 = *(float2*)&d0, g1 = *(float2*)&d1;
            float2 g2 = *(float2*)&d2, g3 = *(float2*)&d3;
            a0 = g0.x * f0 + g1.x * f1 + g2.x * f2 + g3.x * f3;
            a1 = g0.y * f0 + g1.y * f1 + g2.y * f2 + g3.y * f3;
        }
        double gpair = cohLd((const double*)&exch[b * 1024 + 512 + k2]);
        float2 g2v = *(float2*)&gpair;
        float2 o = make_float2(a0 * inv * sigm(g2v.x), a1 * inv * sigm(g2v.y));
        *(float2*)&aweG[b * 512 + k2] = o;   // kernel-end release covers next dispatch
    }
}

// ======== per-step kernel B: gates = [emb|awe]@W2 + h@W3 + cpre; LSTM ========
// PRE=1: emb-contribution precomputed in cpre2 (4 awe + 4 hh chunks).
// PRE=0: 12 chunks (emb, awe, hh); cpre = clspre.
template<int PRE>
__global__ __launch_bounds__(256)
void gatestep_kernel(const float* __restrict__ embW, const float* __restrict__ W2p,
                     const float* __restrict__ W3p, const float* __restrict__ cpre,
                     const float* __restrict__ aweG, const float* __restrict__ hG,
                     const int* __restrict__ caps_i, const int* __restrict__ declen,
                     float* __restrict__ hOut, float* __restrict__ cG,
                     float* __restrict__ hall, int t) {
    const int j = blockIdx.x, tid = threadIdx.x;
    const int lane = tid & 63, wvid = tid >> 6;
    const int d0 = j * 2;
    const int NCH = PRE ? 8 : 12;
    const int WST = PRE ? 516 : 1028;
    __shared__ float stage[64 * 132];
    __shared__ float W2res[8 * 1028];
    __shared__ float W3res[8 * 516];
    __shared__ float Gs[8 * 66];
    __shared__ float CsS[64 * 8];
    __shared__ int capS[64];
    __shared__ int declen_s[64];

    if (PRE) {
        for (int idx = tid; idx < 1024; idx += 256) {
            int cc = idx >> 7, pos = (idx & 127) << 2;
            *(float4*)&W2res[cc * 516 + pos] =
                *(const float4*)&W2p[(size_t)j * 8192 + cc * 1024 + 512 + pos];
        }
    } else {
        for (int idx = tid; idx < 2048; idx += 256) {
            int cc = idx >> 8, pos = (idx & 255) << 2;
            *(float4*)&W2res[cc * 1028 + pos] =
                *(const float4*)&W2p[(size_t)j * 8192 + cc * 1024 + pos];
        }
    }
    for (int idx = tid; idx < 1024; idx += 256) {
        int cc = idx >> 7, pos = (idx & 127) << 2;
        *(float4*)&W3res[cc * 516 + pos] =
            *(const float4*)&W3p[(size_t)j * 4096 + cc * 512 + pos];
    }
    for (int idx = tid; idx < 512; idx += 256) {
        int r = idx >> 3, cc = idx & 7;
        CsS[idx] = cpre[(r << 11) + ((cc >> 1) << 9) + d0 + (cc & 1)];
    }
    if (tid < 64) {
        if (!PRE) capS[tid] = caps_i[tid * MAXLEN + t];
        declen_s[tid] = declen[tid];
    }

    float ac0 = 0.f, ac1 = 0.f;
    for (int ch = 0; ch < NCH; ch++) {
        __syncthreads();
        {
            const float4* src;
            if (PRE) {
                src = (ch < 4)
                    ? (const float4*)(aweG + ((size_t)lane << 9) + (ch << 7) + (wvid << 5))
                    : (const float4*)(hG + ((size_t)lane << 9) + ((ch - 4) << 7) + (wvid << 5));
            } else {
                if (ch < 4)
                    src = (const float4*)(embW + ((size_t)capS[lane] << 9) + (ch << 7) + (wvid << 5));
                else if (ch < 8)
                    src = (const float4*)(aweG + ((size_t)lane << 9) + ((ch - 4) << 7) + (wvid << 5));
                else
                    src = (const float4*)(hG + ((size_t)lane << 9) + ((ch - 8) << 7) + (wvid << 5));
            }
            float4 tmp[8];
#pragma unroll
            for (int i = 0; i < 8; i++) tmp[i] = src[i];
#pragma unroll
            for (int i = 0; i < 8; i++)
                *(float4*)&stage[lane * 132 + (wvid << 5) + (i << 2)] = tmp[i];
        }
        __syncthreads();
        const float* sp = &stage[lane * 132];
        const int hh0 = PRE ? 4 : 8;
        const float* v0p = (ch < hh0) ? &W2res[wvid * WST + (ch << 7)]
                                      : &W3res[wvid * 516 + ((ch - hh0) << 7)];
        const float* v1p = (ch < hh0) ? &W2res[(wvid + 4) * WST + (ch << 7)]
                                      : &W3res[(wvid + 4) * 516 + ((ch - hh0) << 7)];
#pragma unroll 8
        for (int kk = 0; kk < 128; kk += 4) {
            float4 av = *(const float4*)(sp + kk);
            float4 u0 = *(const float4*)(v0p + kk);
            float4 u1 = *(const float4*)(v1p + kk);
            ac0 = fmaf(av.x, u0.x, fmaf(av.y, u0.y, fmaf(av.z, u0.z, fmaf(av.w, u0.w, ac0))));
            ac1 = fmaf(av.x, u1.x, fmaf(av.y, u1.y, fmaf(av.z, u1.z, fmaf(av.w, u1.w, ac1))));
        }
    }
    Gs[wvid * 66 + lane]       = ac0 + CsS[(lane << 3) + wvid];
    Gs[(wvid + 4) * 66 + lane] = ac1 + CsS[(lane << 3) + wvid + 4];
    __syncthreads();
    if (tid < 128) {
        int r2 = tid & 63, dd = tid >> 6;
        if (t < declen_s[r2]) {
            float iv = Gs[(0 + dd) * 66 + r2];
            float fv = Gs[(2 + dd) * 66 + r2];
            float gv = Gs[(4 + dd) * 66 + r2];
            float ov = Gs[(6 + dd) * 66 + r2];
            float cold = cG[r2 * 512 + d0 + dd];
            float cn = sigm(fv) * cold + sigm(iv) * tanhf(gv);
            float hn = sigm(ov) * tanhf(cn);
            cG[r2 * 512 + d0 + dd] = cn;
            hOut[r2 * 512 + d0 + dd] = hn;
            hall[((size_t)r2 * MAXT + t) * 512 + d0 + dd] = hn;
        }
    }
}

// ---------------- FC: 3264x10000, K=512 — 64x128 tile, 4x8/thread ----------------
__global__ __launch_bounds__(256)
void fc_kernel(const float* __restrict__ hall, const float* __restrict__ fcW,
               const float* __restrict__ fcb, const int* __restrict__ declen,
               float* __restrict__ out) {
    __shared__ float As[16][68];
    __shared__ float Bs[16][132];
    int tid = threadIdx.x;
    int n0 = blockIdx.x * 128, m0 = blockIdx.y * 64;
    int tx = tid & 15, ty = tid >> 4;
    int lm = tid >> 2, lk4 = (tid & 3) * 4;
    int bkk = tid >> 4, bnn8 = (tid & 15) * 8;
    const float* arow = hall + (size_t)(m0 + lm) * DECD;
    bool nfull = (n0 + 128 <= VOC);
    float acc[4][8] = {};
    for (int k0 = 0; k0 < 512; k0 += 16) {
        float4 av = *(const float4*)(arow + k0 + lk4);
        float4 bv0, bv1;
        const float* bp = fcW + (size_t)(k0 + bkk) * VOC;
        if (nfull) {
            bv0 = *(const float4*)(bp + n0 + bnn8);
            bv1 = *(const float4*)(bp + n0 + bnn8 + 4);
        } else {
            int nb = n0 + bnn8;
            float tv[8];
#pragma unroll
            for (int u = 0; u < 8; u++) tv[u] = (nb + u < VOC) ? bp[nb + u] : 0.f;
            bv0 = make_float4(tv[0], tv[1], tv[2], tv[3]);
            bv1 = make_float4(tv[4], tv[5], tv[6], tv[7]);
        }
        __syncthreads();
        As[lk4 + 0][lm] = av.x; As[lk4 + 1][lm] = av.y;
        As[lk4 + 2][lm] = av.z; As[lk4 + 3][lm] = av.w;
        *(float4*)&Bs[bkk][bnn8] = bv0;
        *(float4*)&Bs[bkk][bnn8 + 4] = bv1;
        __syncthreads();
#pragma unroll
        for (int kk = 0; kk < 16; kk++) {
            float4 a4 = *(const float4*)&As[kk][ty * 4];
            float4 b40 = *(const float4*)&Bs[kk][tx * 8];
            float4 b41 = *(const float4*)&Bs[kk][tx * 8 + 4];
            float a[4] = {a4.x, a4.y, a4.z, a4.w};
#pragma unroll
            for (int i = 0; i < 4; i++) {
                acc[i][0] = fmaf(a[i], b40.x, acc[i][0]);
                acc[i][1] = fmaf(a[i], b40.y, acc[i][1]);
                acc[i][2] = fmaf(a[i], b40.z, acc[i][2]);
                acc[i][3] = fmaf(a[i], b40.w, acc[i][3]);
                acc[i][4] = fmaf(a[i], b41.x, acc[i][4]);
                acc[i][5] = fmaf(a[i], b41.y, acc[i][5]);
                acc[i][6] = fmaf(a[i], b41.z, acc[i][6]);
                acc[i][7] = fmaf(a[i], b41.w, acc[i][7]);
            }
        }
    }
#pragma unroll
    for (int i = 0; i < 4; i++) {
        int m = m0 + ty * 4 + i;
        int b = m / MAXT, tq = m - b * MAXT;
        bool act = tq < declen[b];
        int n = n0 + tx * 8;
        if (nfull) {
            float4 o0, o1;
            o0.x = act ? acc[i][0] + fcb[n + 0] : 0.f;
            o0.y = act ? acc[i][1] + fcb[n + 1] : 0.f;
            o0.z = act ? acc[i][2] + fcb[n + 2] : 0.f;
            o0.w = act ? acc[i][3] + fcb[n + 3] : 0.f;
            o1.x = act ? acc[i][4] + fcb[n + 4] : 0.f;
            o1.y = act ? acc[i][5] + fcb[n + 5] : 0.f;
            o1.z = act ? acc[i][6] + fcb[n + 6] : 0.f;
            o1.w = act ? acc[i][7] + fcb[n + 7] : 0.f;
            *(float4*)(out + (size_t)m * VOC + n) = o0;
            *(float4*)(out + (size_t)m * VOC + n + 4) = o1;
        } else {
#pragma unroll
            for (int jj = 0; jj < 8; jj++) {
                int nn = n + jj;
                if (nn < VOC) out[(size_t)m * VOC + nn] = act ? acc[i][jj] + fcb[nn] : 0.f;
            }
        }
    }
}

extern "C" void kernel_launch(void* const* d_in, const int* in_sizes, int n_in,
                              void* d_out, int out_size, void* d_ws, size_t ws_size,
                              hipStream_t stream) {
    const float* enc     = (const float*)d_in[0];
    const int*   ecaps   = (const int*)d_in[1];
    const int*   lens    = (const int*)d_in[2];
    const int*   classk  = (const int*)d_in[3];
    const float* embW    = (const float*)d_in[4];
    const float* clsW    = (const float*)d_in[5];
    const float* encattW = (const float*)d_in[6];
    const float* encattb = (const float*)d_in[7];
    const float* decattW = (const float*)d_in[8];
    const float* decattb = (const float*)d_in[9];
    const float* fullw   = (const float*)d_in[10];
    const float* fullb   = (const float*)d_in[11];
    const float* ihW     = (const float*)d_in[12];
    const float* ihb     = (const float*)d_in[13];
    const float* icW     = (const float*)d_in[14];
    const float* icb     = (const float*)d_in[15];
    const float* fbW     = (const float*)d_in[16];
    const float* fbb     = (const float*)d_in[17];
    const float* Wih     = (const float*)d_in[18];
    const float* Whh     = (const float*)d_in[19];
    const float* bih     = (const float*)d_in[20];
    const float* bhh     = (const float*)d_in[21];
    const float* fcW     = (const float*)d_in[22];
    const float* fcb     = (const float*)d_in[23];

    float* out = (float*)d_out;
    float* ws  = (float*)d_ws;
    int*   wsi = (int*)d_ws;

    int*   sortind = wsi + W_SORT;
    int*   declen  = wsi + W_DECLEN;
    int*   caps_i  = wsi + W_CAPS;
    float* cls     = ws + W_CLS;
    float* h       = ws + W_H;
    float* c       = ws + W_C;
    float* initin  = ws + W_ININ;
    float* exch    = ws + W_EXCH;
    float* awe     = ws + W_AWE;
    float* clspre  = ws + W_CLSPRE;
    float* W3p     = ws + W_W3P;
    float* W2p     = ws + W_W2P;
    float* hall    = ws + W_HALL;
    float* att1    = ws + W_ATT1;
    int*   cntP    = wsi + W_CNTP;
    int*   cntX    = wsi + W_CNTX;
    float* pawe    = ws + W_PAWE;
    float* cpre2   = ws + W_CPRE2;

    const bool pre = ws_size >= W_END * 4;   // cpre2 fits in workspace?

    setup_kernel<<<1, 64, 0, stream>>>(lens, out, sortind, declen, cntP);
    gather_kernel<<<141, 256, 0, stream>>>(ecaps, classk, clsW, sortind, caps_i, cls, out);
    mean_cls_kernel<<<BB, 256, 0, stream>>>(enc, cls, sortind, initin);
    init_hc_kernel<<<256, 256, 0, stream>>>(initin, ihW, ihb, icW, icb, h, c);
    pack_w2p_kernel<<<8192, 256, 0, stream>>>(Wih, W2p);
    pack_w3p_kernel<<<4096, 256, 0, stream>>>(Whh, W3p);
    att1_kernel<<<dim3(8, 196), 256, 0, stream>>>(enc, encattW, encattb, sortind, att1);
    clspre_kernel<<<32, 256, 0, stream>>>(cls, Wih, bih, bhh, clspre);
    if (pre)
        embpre_kernel<<<dim3(32, 51), 256, 0, stream>>>(embW, Wih, clspre, caps_i, cpre2);

    for (int t = 0; t < MAXT; t++) {
        attq_kernel<<<256, 256, 0, stream>>>(att1, enc, h, decattW, fbW,
                                             decattb, fbb, fullw, fullb,
                                             sortind, declen, exch, pawe,
                                             cntX, cntP, awe, t);
        if (pre)
            gatestep_kernel<1><<<256, 256, 0, stream>>>(embW, W2p, W3p,
                cpre2 + (size_t)t * 64 * G4, awe, h, caps_i, declen, h, c, hall, t);
        else
            gatestep_kernel<0><<<256, 256, 0, stream>>>(embW, W2p, W3p,
                clspre, awe, h, caps_i, declen, h, c, hall, t);
    }

    fc_kernel<<<dim3(79, 51), 256, 0, stream>>>(hall, fcW, fcb, declen, out);
}